// Round 17
// baseline (428.106 us; speedup 1.0000x reference)
//
#include <hip/hip_runtime.h>
#include <stdint.h>

typedef __attribute__((ext_vector_type(8))) short bf16x8;
typedef __attribute__((ext_vector_type(4))) float f32x4;
typedef __attribute__((ext_vector_type(16))) float f32x16;

__device__ __forceinline__ ushort f2bf(float f) {
  uint32_t u = __builtin_bit_cast(uint32_t, f);
  u += 0x7fffu + ((u >> 16) & 1u);  // RNE
  return (ushort)(u >> 16);
}

__device__ __forceinline__ void async_copy16(const void* gsrc, void* ldst) {
  __builtin_amdgcn_global_load_lds(
      (const __attribute__((address_space(1))) void*)gsrc,
      (__attribute__((address_space(3))) void*)ldst, 16, 0, 0);
}

// ---------------- style linears (all three in one launch; z selects matrix)
__global__ void style_linear3(const float* __restrict__ w,
                              const float* __restrict__ sW1, const float* __restrict__ sb1,
                              const float* __restrict__ sW2, const float* __restrict__ sb2,
                              const float* __restrict__ sW3, const float* __restrict__ sb3,
                              float* __restrict__ A1, float* __restrict__ A2,
                              float* __restrict__ A3) {
  const int which = blockIdx.z;
  const float* sW = (which == 0) ? sW1 : (which == 1) ? sW2 : sW3;
  const float* sb = (which == 0) ? sb1 : (which == 1) ? sb2 : sb3;
  float* A = (which == 0) ? A1 : (which == 1) ? A2 : A3;
  const int b = blockIdx.y;
  const int lane = threadIdx.x & 63, wv = threadIdx.x >> 6;
  const int co = blockIdx.x * 4 + wv;
  const float c = 0.04419417382415922f;  // 1/sqrt(512)
  const float* wr = w + b * 512;
  const float* Wr = sW + (size_t)co * 512;
  float s = 0.f;
#pragma unroll
  for (int i = 0; i < 8; ++i) {
    const int d = i * 64 + lane;
    s += wr[d] * Wr[d];
  }
#pragma unroll
  for (int off = 32; off; off >>= 1) s += __shfl_xor(s, off);
  if (lane == 0) A[b * 512 + co] = s * c + sb[co];
}

// ---------------- fused weight prep + sigma (Wt[tap][co][ci])
__global__ void prep_sigma(const float* __restrict__ Wc, const float* __restrict__ A,
                           ushort* __restrict__ Wt, float* __restrict__ sig) {
  const int co = blockIdx.x;   // 512
  const int ci = threadIdx.x;  // 512
  const int lane = ci & 63, wid = ci >> 6;
  const float c = 0.014731391274719738f;  // 1/sqrt(512*9)
  const float* src = Wc + ((size_t)co * 512 + ci) * 9;
  float s = 0.f;
#pragma unroll
  for (int t = 0; t < 9; ++t) {
    float v = src[t] * c;
    Wt[(size_t)t * 262144 + co * 512 + ci] = f2bf(v);
    s += v * v;
  }
  __shared__ float red[8][8];
#pragma unroll
  for (int b = 0; b < 8; ++b) {
    float a = A[b * 512 + ci];
    float v = s * a * a;
#pragma unroll
    for (int off = 32; off; off >>= 1) v += __shfl_xor(v, off);
    if (lane == 0) red[b][wid] = v;
  }
  __syncthreads();
  if (ci < 8) {
    float t = 0.f;
#pragma unroll
    for (int wv = 0; wv < 8; ++wv) t += red[ci][wv];
    sig[ci * 512 + co] = rsqrtf(t + 1e-8f);
  }
}

// ---------------- zero borders of both padded NHWC buffers + FULL outrgb (24576 uint4)
__global__ void zero_border(uint4* __restrict__ x1, uint4* __restrict__ x2,
                            uint4* __restrict__ rgb) {
  const int i = blockIdx.x * 256 + threadIdx.x;
  const int per = 16640;       // uint4 per batch
  const int tot = per * 8;     // per buffer
  if (i >= 2 * tot) {
    const int j = i - 2 * tot;
    if (j < 24576) rgb[j] = make_uint4(0u, 0u, 0u, 0u);
    return;
  }
  uint4* base = (i < tot) ? x1 : x2;
  int t = (i < tot) ? i : i - tot;
  const int bb = t / per;
  int r = t - bb * per;
  int row, cell, q;
  if (r < 8448) {
    row = (r >= 4224) ? 65 : 0;
    int pos = (r >= 4224) ? r - 4224 : r;
    cell = pos >> 6;
    q = pos & 63;
  } else {
    int r2 = r - 8448;
    row = 1 + (r2 >> 7);
    cell = ((r2 >> 6) & 1) ? 65 : 0;
    q = r2 & 63;
  }
  base[(((size_t)bb * 66 + row) * 66 + cell) * 64 + q] = make_uint4(0u, 0u, 0u, 0u);
}

// ---------------- modulate + NCHW f32 -> padded NHWC bf16 transpose
__global__ void mod_transpose(const float* __restrict__ X, const float* __restrict__ A,
                              ushort* __restrict__ xs) {
  __shared__ float tile[128][65];
  const int h = blockIdx.x;
  const int ci0 = blockIdx.y * 128;
  const int b = blockIdx.z;
  const int tid = threadIdx.x;
  const int wcol = tid & 63;
  const int r0 = tid >> 6;
#pragma unroll 4
  for (int i = 0; i < 32; ++i) {
    const int cil = r0 + i * 4;
    const int ci = ci0 + cil;
    const size_t off = ((size_t)(b * 512 + ci) * 64 + h) * 64 + wcol;
    tile[cil][wcol] = X[off] * A[b * 512 + ci];
  }
  __syncthreads();
  const int sub = tid & 3;
  const int w = tid >> 2;
  ushort* dst = xs + (((size_t)b * 66 + (h + 1)) * 66 + (w + 1)) * 512 + ci0 + sub * 32;
#pragma unroll
  for (int g = 0; g < 4; ++g) {
    bf16x8 v;
#pragma unroll
    for (int j = 0; j < 8; ++j) v[j] = (short)f2bf(tile[sub * 32 + g * 8 + j][w]);
    *(bf16x8*)(dst + g * 8) = v;
  }
}

// ---------------- conv: 256x256 tile, ring-of-4, full-slice read-ahead,
// NOW 32x32x16 MFMA (2382 vs 2075 TF measured): per-slice MFMA 1242->1033 cyc,
// half the matrix instructions; LDS traffic unchanged (12x b128/wave).
#define WAITVM(N) __builtin_amdgcn_s_waitcnt(0x0F70 | (N))

#define READS(S, AF, BV)                                                     \
  do {                                                                       \
    const int q_ = (S) & 3;                                                  \
    const char* baA = (const char*)(&smA[0][0] + q_ * 8192);                 \
    const char* baB = (const char*)(&smB[0][0] + q_ * 8192);                 \
    _Pragma("unroll") for (int r_ = 0; r_ < 8; ++r_)                         \
        AF[r_] = *(const bf16x8*)(baA + aro[r_]);                            \
    _Pragma("unroll") for (int r_ = 0; r_ < 4; ++r_)                         \
        BV[r_] = *(const bf16x8*)(baB + bro[r_]);                            \
  } while (0)

// PH(phase S): MFMA slice S from (MAF,MBV); read slice S+1 into (RAF,RBV)
#define PH(S, WN, DOREAD, DOSTAGE, RAF, RBV, MAF, MBV)                               \
  do {                                                                               \
    WAITVM(WN);                                                                      \
    __builtin_amdgcn_s_barrier();                                                    \
    __builtin_amdgcn_sched_barrier(0);                                               \
    if (DOREAD) READS((S) + 1, RAF, RBV);                                            \
    if (DOSTAGE) stage((S) + 3);                                                     \
    __builtin_amdgcn_sched_barrier(0);                                               \
    __builtin_amdgcn_s_setprio(1);                                                   \
    _Pragma("unroll") for (int mi_ = 0; mi_ < 4; ++mi_)                              \
      _Pragma("unroll") for (int ni_ = 0; ni_ < 2; ++ni_)                            \
        _Pragma("unroll") for (int ks_ = 0; ks_ < 2; ++ks_)                          \
          acc[mi_][ni_] = __builtin_amdgcn_mfma_f32_32x32x16_bf16(                   \
              MAF[mi_ * 2 + ks_], MBV[ni_ * 2 + ks_], acc[mi_][ni_], 0, 0, 0);       \
    __builtin_amdgcn_s_setprio(0);                                                   \
    __builtin_amdgcn_sched_barrier(0);                                               \
  } while (0)

template <int OUT_MODE>
__global__ __launch_bounds__(512, 2) void conv3x3(
    const ushort* __restrict__ xs, const ushort* __restrict__ Wt,
    const float* __restrict__ sig, const float* __restrict__ noise,
    const float* __restrict__ scale_noise, const float* __restrict__ bias,
    const float* __restrict__ amod, void* __restrict__ outp,
    const float* __restrict__ rgbw, const float* __restrict__ arr,
    float* __restrict__ outrgb) {
  __shared__ __align__(16) ushort smA[4][8192];  // 4-slot ring, A slice 256co x 32ci
  __shared__ __align__(16) ushort smB[4][8192];  // 4-slot ring, B slice 256px x 32ci
  const int tid = threadIdx.x, lane = tid & 63, wid = tid >> 6;
  const int wr = wid >> 2, wc = wid & 3;
  // XCD-locality remap: batch = id%8 (round-robin XCD), tile = id/8
  const int id = blockIdx.x;
  const int b = id & 7;
  const int tile = id >> 3;  // 0..31
  const int co0 = (tile & 1) * 256;
  const int px0 = (tile >> 1) * 256;
  const int h0 = px0 >> 6;

  // staging: dest = wavebase + lane*16 (HW-linear); source ci-slot pre-swizzled [rule #21]
  const int sswz = ((lane & 3) ^ ((lane >> 3) & 3)) * 8;  // ushort units
  int aoff[2], boff[2];
  ushort *ldsA[2], *ldsB[2];
#pragma unroll
  for (int i = 0; i < 2; ++i) {
    const int row = (i * 8 + wid) * 16 + (lane >> 2);
    aoff[i] = (co0 + row) * 512 + sswz;
    const int hh = h0 + (row >> 6), ww = row & 63;
    boff[i] = ((b * 66 + hh) * 66 + ww) * 512 + sswz;
    ldsA[i] = &smA[0][0] + (i * 8 + wid) * 512 + lane * 8;
    ldsB[i] = &smB[0][0] + (i * 8 + wid) * 512 + lane * 8;
  }
  // fragment read byte offsets for 32x32x16: row = block + (lane&31),
  // k-slot = ks*2 + (lane>>5), physically XOR-swizzled by ((row>>1)&3) = ((lane>>1)&3)
  int aro[8], bro[4];
#pragma unroll
  for (int mi = 0; mi < 4; ++mi)
#pragma unroll
    for (int ks = 0; ks < 2; ++ks)
      aro[mi * 2 + ks] = (wr * 128 + mi * 32 + (lane & 31)) * 64 +
                         (((ks * 2 + (lane >> 5)) ^ ((lane >> 1) & 3)) << 4);
#pragma unroll
  for (int ni = 0; ni < 2; ++ni)
#pragma unroll
    for (int ks = 0; ks < 2; ++ks)
      bro[ni * 2 + ks] = (wc * 64 + ni * 32 + (lane & 31)) * 64 +
                         (((ks * 2 + (lane >> 5)) ^ ((lane >> 1) & 3)) << 4);

  f32x16 acc[4][2];
#pragma unroll
  for (int mi = 0; mi < 4; ++mi)
#pragma unroll
    for (int ni = 0; ni < 2; ++ni)
#pragma unroll
      for (int r = 0; r < 16; ++r) acc[mi][ni][r] = 0.f;

  auto stage = [&](int s) {
    const int tap = s >> 4;
    const int ci0 = (s & 15) << 5;
    const int kh = tap / 3;
    const int kw = tap - kh * 3;
    const int q = s & 3;
    const ushort* Wb = Wt + tap * 262144 + ci0;
    const ushort* Xb = xs + (kh * 66 + kw) * 512 + ci0;
    async_copy16(Wb + aoff[0], ldsA[0] + q * 8192);
    async_copy16(Wb + aoff[1], ldsA[1] + q * 8192);
    async_copy16(Xb + boff[0], ldsB[0] + q * 8192);
    async_copy16(Xb + boff[1], ldsB[1] + q * 8192);
  };

  // double fragment banks (full-slice lookahead)
  bf16x8 afA[8], bvA[4], afB[8], bvB[4];

  // prologue: stage ring slots 0..2; prime bank A with slice 0
  stage(0);
  stage(1);
  stage(2);
  WAITVM(8);
  __builtin_amdgcn_s_barrier();
  __builtin_amdgcn_sched_barrier(0);
  READS(0, afA, bvA);

  // main: 144 phases; phase p MFMAs slice p, reads slice p+1
  for (int s = 0; s < 140; s += 2) {
    PH(s, 4, true, true, afB, bvB, afA, bvA);
    PH(s + 1, 4, true, true, afA, bvA, afB, bvB);
  }
  PH(140, 4, true, true, afB, bvB, afA, bvA);   // stages slice 143
  PH(141, 4, true, false, afA, bvA, afB, bvB);
  PH(142, 0, true, false, afB, bvB, afA, bvA);
  PH(143, 0, false, false, afA, bvA, afB, bvB);

  // epilogue (32x32 C/D layout: col=lane&31, row=(reg&3)+8*(reg>>2)+4*(lane>>5))
  const float sn = scale_noise[0];
  const int pxl = lane & 31;
  const int rh = (lane >> 5) * 4;
  float nz[2];
#pragma unroll
  for (int ni = 0; ni < 2; ++ni)
    nz[ni] = sn * noise[b * 4096 + px0 + wc * 64 + ni * 32 + pxl];
  float rgbp[3][2];
#pragma unroll
  for (int c = 0; c < 3; ++c)
#pragma unroll
    for (int ni = 0; ni < 2; ++ni) rgbp[c][ni] = 0.f;
#pragma unroll
  for (int mi = 0; mi < 4; ++mi) {
#pragma unroll
    for (int g = 0; g < 4; ++g) {
      const int cob = co0 + wr * 128 + mi * 32 + g * 8 + rh;
      float sg[4], bs[4], am[4];
      float w0[4], w1[4], w2[4];
#pragma unroll
      for (int r = 0; r < 4; ++r) {
        sg[r] = sig[b * 512 + cob + r];
        bs[r] = bias[cob + r];
        if (OUT_MODE == 0) {
          am[r] = amod[b * 512 + cob + r];
        } else {
          const float a3 = arr[b * 512 + cob + r] * 0.04419417382415922f;
          w0[r] = rgbw[cob + r] * a3;
          w1[r] = rgbw[512 + cob + r] * a3;
          w2[r] = rgbw[1024 + cob + r] * a3;
        }
      }
#pragma unroll
      for (int ni = 0; ni < 2; ++ni) {
        const int px = px0 + wc * 64 + ni * 32 + pxl;
        if (OUT_MODE == 0) {
          const int hh = px >> 6, ww = px & 63;
          ushort pk[4];
#pragma unroll
          for (int r = 0; r < 4; ++r) {
            float v = acc[mi][ni][g * 4 + r] * sg[r] + nz[ni] + bs[r];
            v = (v > 0.f) ? v : 0.2f * v;
            pk[r] = f2bf(v * am[r]);
          }
          uint2 u;
          u.x = (uint32_t)pk[0] | ((uint32_t)pk[1] << 16);
          u.y = (uint32_t)pk[2] | ((uint32_t)pk[3] << 16);
          *(uint2*)((ushort*)outp + (((size_t)b * 66 + hh + 1) * 66 + (ww + 1)) * 512 + cob) = u;
        } else {
#pragma unroll
          for (int r = 0; r < 4; ++r) {
            float v = acc[mi][ni][g * 4 + r] * sg[r] + nz[ni] + bs[r];
            v = (v > 0.f) ? v : 0.2f * v;
            ((float*)outp)[((size_t)b * 512 + cob + r) * 4096 + px] = v;
            rgbp[0][ni] += w0[r] * v;
            rgbp[1][ni] += w1[r] * v;
            rgbp[2][ni] += w2[r] * v;
          }
        }
      }
    }
  }
  if (OUT_MODE == 1) {
    // lanes l and l+32 share px; after xor-32 reduce, lanes<32 hold full sums
#pragma unroll
    for (int c = 0; c < 3; ++c)
#pragma unroll
      for (int ni = 0; ni < 2; ++ni) {
        float s = rgbp[c][ni];
        s += __shfl_xor(s, 32);
        if (lane < 32)
          atomicAdd(&outrgb[((size_t)b * 3 + c) * 4096 + px0 + wc * 64 + ni * 32 + lane], s);
      }
  }
}

// ---------------- RGB finish: add bias, leaky relu
__global__ void rgb_finish(float* __restrict__ o, const float* __restrict__ rb) {
  const int i = blockIdx.x * 256 + threadIdx.x;
  if (i >= 98304) return;
  const int c = (i >> 12) % 3;
  float v = o[i] + rb[c];
  o[i] = (v > 0.f) ? v : 0.2f * v;
}

extern "C" void kernel_launch(void* const* d_in, const int* in_sizes, int n_in,
                              void* d_out, int out_size, void* d_ws, size_t ws_size,
                              hipStream_t stream) {
  const float* x     = (const float*)d_in[0];
  const float* w     = (const float*)d_in[1];
  const float* noise = (const float*)d_in[2];
  const float* s1_sW = (const float*)d_in[3];
  const float* s1_sb = (const float*)d_in[4];
  const float* s1_cW = (const float*)d_in[5];
  const float* s1_sn = (const float*)d_in[6];
  const float* s1_b  = (const float*)d_in[7];
  const float* s2_sW = (const float*)d_in[8];
  const float* s2_sb = (const float*)d_in[9];
  const float* s2_cW = (const float*)d_in[10];
  const float* s2_sn = (const float*)d_in[11];
  const float* s2_b  = (const float*)d_in[12];
  const float* r_sW  = (const float*)d_in[13];
  const float* r_sb  = (const float*)d_in[14];
  const float* r_cW  = (const float*)d_in[15];
  const float* r_b   = (const float*)d_in[16];

  char* ws = (char*)d_ws;
  float*  A1  = (float*)(ws + 0);
  float*  A2  = (float*)(ws + 16384);
  float*  Arr = (float*)(ws + 32768);
  float*  sg1 = (float*)(ws + 49152);
  float*  sg2 = (float*)(ws + 65536);
  ushort* Wt1 = (ushort*)(ws + 98304);            // 4.5 MB
  ushort* xs1 = (ushort*)(ws + 4816896);          // padded NHWC, 35.7 MB
  ushort* Wt2 = (ushort*)(ws + 4816896);          // aliases xs1 (used after conv1)
  ushort* xs2 = (ushort*)(ws + 40501248);         // padded NHWC, 35.7 MB
  float* outx   = (float*)d_out;
  float* outrgb = outx + (size_t)8 * 512 * 4096;

  style_linear3<<<dim3(128, 8, 3), 256, 0, stream>>>(w, s1_sW, s1_sb, s2_sW, s2_sb, r_sW,
                                                     r_sb, A1, A2, Arr);

  prep_sigma<<<512, 512, 0, stream>>>(s1_cW, A1, Wt1, sg1);

  zero_border<<<1136, 256, 0, stream>>>((uint4*)xs1, (uint4*)xs2, (uint4*)outrgb);
  mod_transpose<<<dim3(64, 4, 8), 256, 0, stream>>>(x, A1, xs1);

  conv3x3<0><<<dim3(256), 512, 0, stream>>>(xs1, Wt1, sg1, noise, s1_sn, s1_b, A2, (void*)xs2,
                                            r_cW, Arr, outrgb);
  prep_sigma<<<512, 512, 0, stream>>>(s2_cW, A2, Wt2, sg2);  // Wt2 aliases xs1: after conv1
  conv3x3<1><<<dim3(256), 512, 0, stream>>>(xs2, Wt2, sg2, noise + 32768, s2_sn, s2_b, sg2,
                                            (void*)outx, r_cW, Arr, outrgb);
  rgb_finish<<<384, 256, 0, stream>>>(outrgb, r_b);
}

// Round 18
// 313.351 us; speedup vs baseline: 1.3662x; 1.3662x over previous
//
#include <hip/hip_runtime.h>
#include <stdint.h>

typedef __attribute__((ext_vector_type(8))) short bf16x8;
typedef __attribute__((ext_vector_type(4))) float f32x4;

__device__ __forceinline__ ushort f2bf(float f) {
  uint32_t u = __builtin_bit_cast(uint32_t, f);
  u += 0x7fffu + ((u >> 16) & 1u);  // RNE
  return (ushort)(u >> 16);
}

__device__ __forceinline__ void async_copy16(const void* gsrc, void* ldst) {
  __builtin_amdgcn_global_load_lds(
      (const __attribute__((address_space(1))) void*)gsrc,
      (__attribute__((address_space(3))) void*)ldst, 16, 0, 0);
}

// ---------------- style linears (all three in one launch; z selects matrix)
__global__ void style_linear3(const float* __restrict__ w,
                              const float* __restrict__ sW1, const float* __restrict__ sb1,
                              const float* __restrict__ sW2, const float* __restrict__ sb2,
                              const float* __restrict__ sW3, const float* __restrict__ sb3,
                              float* __restrict__ A1, float* __restrict__ A2,
                              float* __restrict__ A3) {
  const int which = blockIdx.z;
  const float* sW = (which == 0) ? sW1 : (which == 1) ? sW2 : sW3;
  const float* sb = (which == 0) ? sb1 : (which == 1) ? sb2 : sb3;
  float* A = (which == 0) ? A1 : (which == 1) ? A2 : A3;
  const int b = blockIdx.y;
  const int lane = threadIdx.x & 63, wv = threadIdx.x >> 6;
  const int co = blockIdx.x * 4 + wv;
  const float c = 0.04419417382415922f;  // 1/sqrt(512)
  const float* wr = w + b * 512;
  const float* Wr = sW + (size_t)co * 512;
  float s = 0.f;
#pragma unroll
  for (int i = 0; i < 8; ++i) {
    const int d = i * 64 + lane;
    s += wr[d] * Wr[d];
  }
#pragma unroll
  for (int off = 32; off; off >>= 1) s += __shfl_xor(s, off);
  if (lane == 0) A[b * 512 + co] = s * c + sb[co];
}

// ---------------- fused weight prep + sigma (Wt[tap][co][ci])
__global__ void prep_sigma(const float* __restrict__ Wc, const float* __restrict__ A,
                           ushort* __restrict__ Wt, float* __restrict__ sig) {
  const int co = blockIdx.x;   // 512
  const int ci = threadIdx.x;  // 512
  const int lane = ci & 63, wid = ci >> 6;
  const float c = 0.014731391274719738f;  // 1/sqrt(512*9)
  const float* src = Wc + ((size_t)co * 512 + ci) * 9;
  float s = 0.f;
#pragma unroll
  for (int t = 0; t < 9; ++t) {
    float v = src[t] * c;
    Wt[(size_t)t * 262144 + co * 512 + ci] = f2bf(v);
    s += v * v;
  }
  __shared__ float red[8][8];
#pragma unroll
  for (int b = 0; b < 8; ++b) {
    float a = A[b * 512 + ci];
    float v = s * a * a;
#pragma unroll
    for (int off = 32; off; off >>= 1) v += __shfl_xor(v, off);
    if (lane == 0) red[b][wid] = v;
  }
  __syncthreads();
  if (ci < 8) {
    float t = 0.f;
#pragma unroll
    for (int wv = 0; wv < 8; ++wv) t += red[ci][wv];
    sig[ci * 512 + co] = rsqrtf(t + 1e-8f);
  }
}

// ---------------- zero borders of both padded NHWC buffers + FULL outrgb (24576 uint4)
__global__ void zero_border(uint4* __restrict__ x1, uint4* __restrict__ x2,
                            uint4* __restrict__ rgb) {
  const int i = blockIdx.x * 256 + threadIdx.x;
  const int per = 16640;       // uint4 per batch
  const int tot = per * 8;     // per buffer
  if (i >= 2 * tot) {
    const int j = i - 2 * tot;
    if (j < 24576) rgb[j] = make_uint4(0u, 0u, 0u, 0u);
    return;
  }
  uint4* base = (i < tot) ? x1 : x2;
  int t = (i < tot) ? i : i - tot;
  const int bb = t / per;
  int r = t - bb * per;
  int row, cell, q;
  if (r < 8448) {
    row = (r >= 4224) ? 65 : 0;
    int pos = (r >= 4224) ? r - 4224 : r;
    cell = pos >> 6;
    q = pos & 63;
  } else {
    int r2 = r - 8448;
    row = 1 + (r2 >> 7);
    cell = ((r2 >> 6) & 1) ? 65 : 0;
    q = r2 & 63;
  }
  base[(((size_t)bb * 66 + row) * 66 + cell) * 64 + q] = make_uint4(0u, 0u, 0u, 0u);
}

// ---------------- modulate + NCHW f32 -> padded NHWC bf16 transpose
__global__ void mod_transpose(const float* __restrict__ X, const float* __restrict__ A,
                              ushort* __restrict__ xs) {
  __shared__ float tile[128][65];
  const int h = blockIdx.x;
  const int ci0 = blockIdx.y * 128;
  const int b = blockIdx.z;
  const int tid = threadIdx.x;
  const int wcol = tid & 63;
  const int r0 = tid >> 6;
#pragma unroll 4
  for (int i = 0; i < 32; ++i) {
    const int cil = r0 + i * 4;
    const int ci = ci0 + cil;
    const size_t off = ((size_t)(b * 512 + ci) * 64 + h) * 64 + wcol;
    tile[cil][wcol] = X[off] * A[b * 512 + ci];
  }
  __syncthreads();
  const int sub = tid & 3;
  const int w = tid >> 2;
  ushort* dst = xs + (((size_t)b * 66 + (h + 1)) * 66 + (w + 1)) * 512 + ci0 + sub * 32;
#pragma unroll
  for (int g = 0; g < 4; ++g) {
    bf16x8 v;
#pragma unroll
    for (int j = 0; j < 8; ++j) v[j] = (short)f2bf(tile[sub * 32 + g * 8 + j][w]);
    *(bf16x8*)(dst + g * 8) = v;
  }
}

// ---------------- conv: 256x256 tile, ring-of-4, full-slice read-ahead,
// T19 sched_group_barrier interleave (champion structure, R13/R16).
#define WAITVM(N) __builtin_amdgcn_s_waitcnt(0x0F70 | (N))
#define SGB __builtin_amdgcn_sched_group_barrier

#define READS(S, AF, BV)                                                     \
  do {                                                                       \
    const int q_ = (S) & 3;                                                  \
    const char* baA = (const char*)(&smA[0][0] + q_ * 8192);                 \
    const char* baB = (const char*)(&smB[0][0] + q_ * 8192);                 \
    _Pragma("unroll") for (int m_ = 0; m_ < 8; ++m_)                         \
        AF[m_] = *(const bf16x8*)(baA + aro[m_]);                            \
    _Pragma("unroll") for (int n_ = 0; n_ < 4; ++n_)                         \
        BV[n_] = *(const bf16x8*)(baB + bro[n_]);                            \
  } while (0)

// PH(phase S): MFMA slice S from (MAF,MBV); read slice S+1 into (RAF,RBV)
#define PH(S, WN, DOREAD, DOSTAGE, RAF, RBV, MAF, MBV)                               \
  do {                                                                               \
    WAITVM(WN);                                                                      \
    __builtin_amdgcn_s_barrier();                                                    \
    __builtin_amdgcn_sched_barrier(0);                                               \
    __builtin_amdgcn_s_setprio(1);                                                   \
    if (DOREAD) READS((S) + 1, RAF, RBV);                                            \
    if (DOSTAGE) stage((S) + 3);                                                     \
    _Pragma("unroll") for (int m_ = 0; m_ < 8; ++m_)                                 \
      _Pragma("unroll") for (int n_ = 0; n_ < 4; ++n_)                               \
        acc[m_][n_] = __builtin_amdgcn_mfma_f32_16x16x32_bf16(MAF[m_], MBV[n_],      \
                                                              acc[m_][n_], 0, 0, 0); \
    SGB(0x8, 2, 0);                                                                  \
    SGB(0x100, 2, 0); SGB(0x8, 4, 0);                                                \
    SGB(0x100, 2, 0); SGB(0x8, 4, 0);                                                \
    SGB(0x100, 2, 0); SGB(0x8, 4, 0);                                                \
    SGB(0x100, 2, 0); SGB(0x8, 4, 0);                                                \
    SGB(0x100, 2, 0); SGB(0x8, 4, 0);                                                \
    SGB(0x100, 2, 0); SGB(0x8, 6, 0);                                                \
    __builtin_amdgcn_s_setprio(0);                                                   \
    __builtin_amdgcn_sched_barrier(0);                                               \
  } while (0)

template <int OUT_MODE>
__global__ __launch_bounds__(512, 2) void conv3x3(
    const ushort* __restrict__ xs, const ushort* __restrict__ Wt,
    const float* __restrict__ sig, const float* __restrict__ noise,
    const float* __restrict__ scale_noise, const float* __restrict__ bias,
    const float* __restrict__ amod, void* __restrict__ outp,
    const float* __restrict__ rgbw, const float* __restrict__ arr,
    float* __restrict__ outrgb) {
  __shared__ __align__(16) ushort smA[4][8192];  // 4-slot ring, A slice 256co x 32ci
  __shared__ __align__(16) ushort smB[4][8192];  // 4-slot ring, B slice 256px x 32ci
  const int tid = threadIdx.x, lane = tid & 63, wid = tid >> 6;
  const int wr = wid >> 2, wc = wid & 3;
  // XCD-locality remap: batch = id%8 (round-robin XCD), tile = id/8
  const int id = blockIdx.x;
  const int b = id & 7;
  const int tile = id >> 3;  // 0..31
  const int co0 = (tile & 1) * 256;
  const int px0 = (tile >> 1) * 256;
  const int h0 = px0 >> 6;

  // staging: dest = wavebase + lane*16 (HW-linear); source ci-slot pre-swizzled [rule #21]
  const int sswz = ((lane & 3) ^ ((lane >> 3) & 3)) * 8;  // ushort units
  int aoff[2], boff[2];
  ushort *ldsA[2], *ldsB[2];
#pragma unroll
  for (int i = 0; i < 2; ++i) {
    const int row = (i * 8 + wid) * 16 + (lane >> 2);
    aoff[i] = (co0 + row) * 512 + sswz;
    const int hh = h0 + (row >> 6), ww = row & 63;
    boff[i] = ((b * 66 + hh) * 66 + ww) * 512 + sswz;
    ldsA[i] = &smA[0][0] + (i * 8 + wid) * 512 + lane * 8;
    ldsB[i] = &smB[0][0] + (i * 8 + wid) * 512 + lane * 8;
  }
  // fragment read byte offsets (swizzled to match)
  const int rdsw = ((lane >> 4) ^ ((lane >> 1) & 3)) * 16;
  int aro[8], bro[4];
#pragma unroll
  for (int m = 0; m < 8; ++m) aro[m] = (wr * 128 + m * 16 + (lane & 15)) * 64 + rdsw;
#pragma unroll
  for (int n = 0; n < 4; ++n) bro[n] = (wc * 64 + n * 16 + (lane & 15)) * 64 + rdsw;

  f32x4 acc[8][4];
#pragma unroll
  for (int m = 0; m < 8; ++m)
#pragma unroll
    for (int n = 0; n < 4; ++n) acc[m][n] = (f32x4){0.f, 0.f, 0.f, 0.f};

  auto stage = [&](int s) {
    const int tap = s >> 4;
    const int ci0 = (s & 15) << 5;
    const int kh = tap / 3;
    const int kw = tap - kh * 3;
    const int q = s & 3;
    const ushort* Wb = Wt + tap * 262144 + ci0;
    const ushort* Xb = xs + (kh * 66 + kw) * 512 + ci0;
    async_copy16(Wb + aoff[0], ldsA[0] + q * 8192);
    async_copy16(Wb + aoff[1], ldsA[1] + q * 8192);
    async_copy16(Xb + boff[0], ldsB[0] + q * 8192);
    async_copy16(Xb + boff[1], ldsB[1] + q * 8192);
  };

  // double fragment banks (full-slice lookahead)
  bf16x8 afA[8], bvA[4], afB[8], bvB[4];

  // prologue: stage ring slots 0..2; prime bank A with slice 0
  stage(0);
  stage(1);
  stage(2);
  WAITVM(8);
  __builtin_amdgcn_s_barrier();
  __builtin_amdgcn_sched_barrier(0);
  READS(0, afA, bvA);

  // main: 144 phases; phase p MFMAs slice p, reads slice p+1
  for (int s = 0; s < 140; s += 2) {
    PH(s, 4, true, true, afB, bvB, afA, bvA);
    PH(s + 1, 4, true, true, afA, bvA, afB, bvB);
  }
  PH(140, 4, true, true, afB, bvB, afA, bvA);   // stages slice 143
  PH(141, 4, true, false, afA, bvA, afB, bvB);
  PH(142, 0, true, false, afB, bvB, afA, bvA);
  PH(143, 0, false, false, afA, bvA, afB, bvB);

  // epilogue: demod, noise, bias, lrelu; OUT_MODE 0 also folds next-layer mod,
  // OUT_MODE 1 also accumulates the fused RGB 1x1 conv partials.
  const float sn = scale_noise[0];
  const int colp = lane & 15;
  const int rq = (lane >> 4) * 4;
  float nz[4];
#pragma unroll
  for (int n = 0; n < 4; ++n)
    nz[n] = sn * noise[b * 4096 + px0 + wc * 64 + n * 16 + colp];
  float rgbp[3][4];
#pragma unroll
  for (int c = 0; c < 3; ++c)
#pragma unroll
    for (int n = 0; n < 4; ++n) rgbp[c][n] = 0.f;
#pragma unroll
  for (int m = 0; m < 8; ++m) {
    const int cob = co0 + wr * 128 + m * 16 + rq;
    float sg[4], bs[4], am[4];
    float w0[4], w1[4], w2[4];
#pragma unroll
    for (int r = 0; r < 4; ++r) {
      sg[r] = sig[b * 512 + cob + r];
      bs[r] = bias[cob + r];
      if (OUT_MODE == 0) {
        am[r] = amod[b * 512 + cob + r];
      } else {
        const float a3 = arr[b * 512 + cob + r] * 0.04419417382415922f;
        w0[r] = rgbw[cob + r] * a3;
        w1[r] = rgbw[512 + cob + r] * a3;
        w2[r] = rgbw[1024 + cob + r] * a3;
      }
    }
#pragma unroll
    for (int n = 0; n < 4; ++n) {
      const int px = px0 + wc * 64 + n * 16 + colp;
      if (OUT_MODE == 0) {
        const int hh = px >> 6, ww = px & 63;
        ushort pk[4];
#pragma unroll
        for (int r = 0; r < 4; ++r) {
          float v = acc[m][n][r] * sg[r] + nz[n] + bs[r];
          v = (v > 0.f) ? v : 0.2f * v;
          pk[r] = f2bf(v * am[r]);
        }
        uint2 u;
        u.x = (uint32_t)pk[0] | ((uint32_t)pk[1] << 16);
        u.y = (uint32_t)pk[2] | ((uint32_t)pk[3] << 16);
        *(uint2*)((ushort*)outp + (((size_t)b * 66 + hh + 1) * 66 + (ww + 1)) * 512 + cob) = u;
      } else {
#pragma unroll
        for (int r = 0; r < 4; ++r) {
          float v = acc[m][n][r] * sg[r] + nz[n] + bs[r];
          v = (v > 0.f) ? v : 0.2f * v;
          ((float*)outp)[((size_t)b * 512 + cob + r) * 4096 + px] = v;
          rgbp[0][n] += w0[r] * v;
          rgbp[1][n] += w1[r] * v;
          rgbp[2][n] += w2[r] * v;
        }
      }
    }
  }
  if (OUT_MODE == 1) {
    // reduce over rquad groups {l, l^16, l^32, l^48}; lanes<16 hold full sums
#pragma unroll
    for (int c = 0; c < 3; ++c)
#pragma unroll
      for (int n = 0; n < 4; ++n) {
        float s = rgbp[c][n];
        s += __shfl_xor(s, 16);
        s += __shfl_xor(s, 32);
        if (lane < 16)
          atomicAdd(&outrgb[((size_t)b * 3 + c) * 4096 + px0 + wc * 64 + n * 16 + colp], s);
      }
  }
}

// ---------------- RGB finish: add bias, leaky relu
__global__ void rgb_finish(float* __restrict__ o, const float* __restrict__ rb) {
  const int i = blockIdx.x * 256 + threadIdx.x;
  if (i >= 98304) return;
  const int c = (i >> 12) % 3;
  float v = o[i] + rb[c];
  o[i] = (v > 0.f) ? v : 0.2f * v;
}

extern "C" void kernel_launch(void* const* d_in, const int* in_sizes, int n_in,
                              void* d_out, int out_size, void* d_ws, size_t ws_size,
                              hipStream_t stream) {
  const float* x     = (const float*)d_in[0];
  const float* w     = (const float*)d_in[1];
  const float* noise = (const float*)d_in[2];
  const float* s1_sW = (const float*)d_in[3];
  const float* s1_sb = (const float*)d_in[4];
  const float* s1_cW = (const float*)d_in[5];
  const float* s1_sn = (const float*)d_in[6];
  const float* s1_b  = (const float*)d_in[7];
  const float* s2_sW = (const float*)d_in[8];
  const float* s2_sb = (const float*)d_in[9];
  const float* s2_cW = (const float*)d_in[10];
  const float* s2_sn = (const float*)d_in[11];
  const float* s2_b  = (const float*)d_in[12];
  const float* r_sW  = (const float*)d_in[13];
  const float* r_sb  = (const float*)d_in[14];
  const float* r_cW  = (const float*)d_in[15];
  const float* r_b   = (const float*)d_in[16];

  char* ws = (char*)d_ws;
  float*  A1  = (float*)(ws + 0);
  float*  A2  = (float*)(ws + 16384);
  float*  Arr = (float*)(ws + 32768);
  float*  sg1 = (float*)(ws + 49152);
  float*  sg2 = (float*)(ws + 65536);
  ushort* Wt1 = (ushort*)(ws + 98304);            // 4.5 MB
  ushort* xs1 = (ushort*)(ws + 4816896);          // padded NHWC, 35.7 MB
  ushort* Wt2 = (ushort*)(ws + 4816896);          // aliases xs1 (used after conv1)
  ushort* xs2 = (ushort*)(ws + 40501248);         // padded NHWC, 35.7 MB
  float* outx   = (float*)d_out;
  float* outrgb = outx + (size_t)8 * 512 * 4096;

  style_linear3<<<dim3(128, 8, 3), 256, 0, stream>>>(w, s1_sW, s1_sb, s2_sW, s2_sb, r_sW,
                                                     r_sb, A1, A2, Arr);

  prep_sigma<<<512, 512, 0, stream>>>(s1_cW, A1, Wt1, sg1);

  zero_border<<<1136, 256, 0, stream>>>((uint4*)xs1, (uint4*)xs2, (uint4*)outrgb);
  mod_transpose<<<dim3(64, 4, 8), 256, 0, stream>>>(x, A1, xs1);

  conv3x3<0><<<dim3(256), 512, 0, stream>>>(xs1, Wt1, sg1, noise, s1_sn, s1_b, A2, (void*)xs2,
                                            r_cW, Arr, outrgb);
  prep_sigma<<<512, 512, 0, stream>>>(s2_cW, A2, Wt2, sg2);  // Wt2 aliases xs1: after conv1
  conv3x3<1><<<dim3(256), 512, 0, stream>>>(xs2, Wt2, sg2, noise + 32768, s2_sn, s2_b, sg2,
                                            (void*)outx, r_cW, Arr, outrgb);
  rgb_finish<<<384, 256, 0, stream>>>(outrgb, r_b);
}